// Round 2
// baseline (23.507 us; speedup 1.0000x reference)
//
#include <hip/hip_runtime.h>
#include <cmath>

#define TT 24
#define STRIDE 217   // odd -> conflict-free LDS banks for per-thread row access
// per-instance LDS row (floats): pg@0 pp@24 ps@48 pc@72 pd@96 dt@120 C@144..215
// after compute, offsets 0..119 hold the output block [dg+dc | dp | ds | dc | dd]

__global__ __launch_bounds__(64) void gru_kernel(
    const float* __restrict__ pi_g, const float* __restrict__ pi_p,
    const float* __restrict__ pi_s, const float* __restrict__ pi_c,
    const float* __restrict__ pi_d, const float* __restrict__ d_t,
    const float* __restrict__ C,    float* __restrict__ out)
{
    __shared__ float lds[64 * STRIDE];
    const int lane  = threadIdx.x;
    const int inst0 = blockIdx.x * 64;

    // ---- stage inputs (coalesced float4 loads -> LDS rows) ----
    const float* srcs[6] = {pi_g, pi_p, pi_s, pi_c, pi_d, d_t};
#pragma unroll
    for (int a = 0; a < 6; ++a) {
        const float4* s4 = reinterpret_cast<const float4*>(srcs[a] + (size_t)inst0 * 24);
#pragma unroll
        for (int j = 0; j < 6; ++j) {               // 64*24/4 = 384 float4 / 64 lanes
            int idx4 = j * 64 + lane;
            float4 v = s4[idx4];
            int w0 = idx4 * 4;
            int inst = w0 / 24, k = w0 % 24;        // 4 | 24 -> never crosses instance
            float* dst = &lds[inst * STRIDE + a * 24 + k];
            dst[0] = v.x; dst[1] = v.y; dst[2] = v.z; dst[3] = v.w;
        }
    }
    {
        const float4* s4 = reinterpret_cast<const float4*>(C + (size_t)inst0 * 72);
#pragma unroll
        for (int j = 0; j < 18; ++j) {              // 64*72/4 = 1152 float4 / 64 lanes
            int idx4 = j * 64 + lane;
            float4 v = s4[idx4];
            int w0 = idx4 * 4;
            int inst = w0 / 72, k = w0 % 72;        // 4 | 72
            float* dst = &lds[inst * STRIDE + 144 + k];
            dst[0] = v.x; dst[1] = v.y; dst[2] = v.z; dst[3] = v.w;
        }
    }
    __syncthreads();

    float* R = &lds[lane * STRIDE];

    // ---- phase A: forward scan over t (O(T) online softmax) ----
    float cs = 0.f, mg = -1e30f, Ss = 0.f;
    float garr[TT], marr[TT], Sarr[TT], rsA[TT];
#pragma unroll
    for (int t = 0; t < TT; ++t) {
        float p_g = R[t];
        float p_p = fmaxf(R[24 + t], 0.f);
        float p_s = fmaxf(R[48 + t], 0.f);
        float p_c = fmaxf(R[72 + t], 0.f);
        float p_d = fmaxf(R[96 + t], 0.f);
        float dt  = R[120 + t];
        float C0 = R[144 + 3 * t], C1 = R[145 + 3 * t], C2 = R[146 + 3 * t];

        // pi_tilda[t] = cs[t] + min_{i<t} f[i] = cs - mg/5  (t=0 -> ~2e29, acts as +inf)
        float pi_t = cs - mg * 0.2f;

        // module 2: cascaded 3-way stable softmaxes (accurate expf: ALPHA=1000 amplifies err)
        float X0 = pi_t + p_d * (1.0f / 0.95f);
        float y0 = -10.f * X0, y1 = -10.f * p_p, y2 = -10.f * p_g;

        float mx1 = fmaxf(fmaxf(y0, y1), y2);
        float e0 = expf(y0 - mx1), e1 = expf(y1 - mx1), e2 = expf(y2 - mx1);
        float rs1 = 1.0f / (e0 + e1 + e2);
        float a10 = e0 * rs1, a11 = e1 * rs1, a12 = e2 * rs1;

        float z0 = y0 - 10000.f * a10, z1 = y1 - 10000.f * a11, z2 = y2 - 10000.f * a12;
        float mx2 = fmaxf(fmaxf(z0, z1), z2);
        float f0 = expf(z0 - mx2), f1 = expf(z1 - mx2), f2 = expf(z2 - mx2);
        float rs2 = 1.0f / (f0 + f1 + f2);
        float a20 = f0 * rs2, a21 = f1 * rs2, a22 = f2 * rs2;

        float w0_ = z0 - 10000.f * a20, w1_ = z1 - 10000.f * a21, w2_ = z2 - 10000.f * a22;
        float mx3 = fmaxf(fmaxf(w0_, w1_), w2_);
        float h0 = expf(w0_ - mx3), h1 = expf(w1_ - mx3), h2 = expf(w2_ - mx3);
        float rs3 = 1.0f / (h0 + h1 + h2);
        float a30 = h0 * rs3, a31 = h1 * rs3, a32 = h2 * rs3;

        // module 4 per-t part
        float delta0 = a10 * C0 + a11 * C1 + a12 * C2;
        float d0 = delta0 - fmaxf(delta0 - dt, 0.f);
        float delta1 = a20 * C0 + a21 * C1 + a22 * C2;
        float d1 = delta1 - fmaxf(delta1 - (dt - d0), 0.f);
        float delta2 = a30 * C0 + a31 * C1 + a32 * C2;
        float d2 = delta2 - fmaxf(delta2 - (dt - d0 - d1), 0.f);

        float dg = a12 * d0 + a22 * d1 + a32 * d2;
        float dp = a11 * d0 + a21 * d1 + a31 * d2;
        float dd = (a10 * d0 + a20 * d1 + a30 * d2) * (1.0f / 0.95f);

        rsA[t] = (t == 0) ? 0.f : dd / Ss;   // r[t] = d_d[t] / S~[t]; row 0 of i_t is zero

        // store per-t outputs into LDS slots whose inputs are now dead
        R[t]      = dg;   // pi_g slot -> becomes row0 (d_g), += d_c in phase B
        R[24 + t] = dp;   // pi_p slot -> row1 (d_p)
        R[96 + t] = dd;   // pi_d slot -> row4 (d_d)

        // f[t], g[t]; online max/sum update AFTER use (exclusive semantics)
        float ft = p_c * (1.0f / (0.95f * 0.95f)) + p_g - cs;
        float gt = -5.f * ft;
        garr[t] = gt;
        float nm = fmaxf(mg, gt);
        Ss = Ss * __expf(mg - nm) + __expf(gt - nm);
        mg = nm;
        marr[t] = mg;   // inclusive prefix max = m[t+1]
        Sarr[t] = Ss;   // inclusive prefix sum = S~[t+1] (scaled at marr[t])
        cs += p_s * (1.0f / 0.95f);
    }

    // ---- phase B: suffix recurrence for d_c, d_s (all exponents <= 0) ----
    R[48 + 23] = 0.f;   // ds[23]
    R[72 + 23] = 0.f;   // dc[23]
    float qs = 0.f;
#pragma unroll
    for (int i = TT - 2; i >= 0; --i) {
        qs = rsA[i + 1] + __expf(marr[i] - marr[i + 1]) * qs;
        float dc = __expf(garr[i] - marr[i]) * qs * (1.0f / 0.95f);
        R[72 + i] = dc;               // row3 (d_c)
        R[48 + i] = Sarr[i] * qs;     // row2 (d_s)
        R[i]     += dc;               // row0 = d_g + d_c
    }
    __syncthreads();

    // ---- cooperative coalesced store: 64 inst x 120 floats ----
    float* ob = out + (size_t)inst0 * 120;
    int k = lane, addr = lane;        // addr = inst*STRIDE + k invariant
#pragma unroll
    for (int j = 0; j < 120; ++j) {
        ob[j * 64 + lane] = lds[addr];
        k += 64; addr += 64;
        if (k >= 120) { k -= 120; addr += (STRIDE - 120); }
    }
}

extern "C" void kernel_launch(void* const* d_in, const int* in_sizes, int n_in,
                              void* d_out, int out_size, void* d_ws, size_t ws_size,
                              hipStream_t stream) {
    const float* pi_g = (const float*)d_in[0];
    const float* pi_p = (const float*)d_in[1];
    const float* pi_s = (const float*)d_in[2];
    const float* pi_c = (const float*)d_in[3];
    const float* pi_d = (const float*)d_in[4];
    const float* d_t  = (const float*)d_in[5];
    const float* C_t  = (const float*)d_in[6];
    float* out = (float*)d_out;

    int n = in_sizes[0] / 24;         // batch = 16384
    int blocks = n / 64;              // 256 blocks x 64 threads (1 instance/thread)
    gru_kernel<<<blocks, 64, 0, stream>>>(pi_g, pi_p, pi_s, pi_c, pi_d, d_t, C_t, out);
}

// Round 3
// 12.421 us; speedup vs baseline: 1.8925x; 1.8925x over previous
//
#include <hip/hip_runtime.h>
#include <cmath>

#define ETA_INV 1.0526315789473684f   // 1/0.95

// One 32-lane group per instance; lane t in [0,24) handles time slot t.
// All per-t scans done with width-32 wave shuffles; no LDS, no barriers.
__global__ __launch_bounds__(256) void gru_kernel(
    const float* __restrict__ pi_g, const float* __restrict__ pi_p,
    const float* __restrict__ pi_s, const float* __restrict__ pi_c,
    const float* __restrict__ pi_d, const float* __restrict__ d_t,
    const float* __restrict__ C,    float* __restrict__ out, int nInst)
{
    const int inst = blockIdx.x * 8 + (threadIdx.x >> 5);
    const int t    = threadIdx.x & 31;
    if (inst >= nInst) return;
    const bool act = (t < 24);

    // ---- loads (lanes 24-31 clamp to t=23; their values never escape) ----
    const int tc = act ? t : 23;
    const size_t b24 = (size_t)inst * 24 + tc;
    float p_g = pi_g[b24];
    float p_p = fmaxf(pi_p[b24], 0.f);
    float p_s = fmaxf(pi_s[b24], 0.f);
    float p_c = fmaxf(pi_c[b24], 0.f);
    float p_d = fmaxf(pi_d[b24], 0.f);
    float dt  = d_t[b24];
    const size_t b72 = (size_t)inst * 72 + 3 * tc;
    float C0 = C[b72], C1 = C[b72 + 1], C2 = C[b72 + 2];

    // ---- scan 1: cs[t] = sum_{k<t} pi_s_eta[k]  (shift + inclusive sum) ----
    float ps_eta = p_s * ETA_INV;
    float cs = __shfl_up(ps_eta, 1, 32);
    if (t == 0) cs = 0.f;
#pragma unroll
    for (int off = 1; off < 32; off <<= 1) {
        float o = __shfl_up(cs, off, 32);
        if (t >= off) cs += o;
    }

    // ---- g[t]; scan 2: online-softmax pair (m,S) inclusive scan ----
    float gt = -5.f * (p_c * (ETA_INV * ETA_INV) + p_g - cs);
    float m = gt, S = 1.f;
#pragma unroll
    for (int off = 1; off < 32; off <<= 1) {
        float mo = __shfl_up(m, off, 32);
        float So = __shfl_up(S, off, 32);
        if (t >= off) {
            float nm = fmaxf(m, mo);
            S = S * __expf(m - nm) + So * __expf(mo - nm);  // exponents <= 0
            m = nm;
        }
    }
    float m_ex = __shfl_up(m, 1, 32);   // exclusive prefix max of g
    float S_ex = __shfl_up(S, 1, 32);   // exclusive scaled sum (at scale m_ex)
    if (t == 0) { m_ex = -1e30f; S_ex = 0.f; }

    // ---- cascade (per-lane, independent): accurate expf (ALPHA amplifies err) ----
    float pi_t = cs - 0.2f * m_ex;                 // t=0 -> ~2e29 acts as +inf
    float X0 = pi_t + p_d * ETA_INV;
    float y0 = -10.f * X0, y1 = -10.f * p_p, y2 = -10.f * p_g;

    float mx1 = fmaxf(fmaxf(y0, y1), y2);
    float e0 = expf(y0 - mx1), e1 = expf(y1 - mx1), e2 = expf(y2 - mx1);
    float rs1 = 1.0f / (e0 + e1 + e2);
    float a10 = e0 * rs1, a11 = e1 * rs1, a12 = e2 * rs1;

    float z0 = y0 - 10000.f * a10, z1 = y1 - 10000.f * a11, z2 = y2 - 10000.f * a12;
    float mx2 = fmaxf(fmaxf(z0, z1), z2);
    float f0 = expf(z0 - mx2), f1 = expf(z1 - mx2), f2 = expf(z2 - mx2);
    float rs2 = 1.0f / (f0 + f1 + f2);
    float a20 = f0 * rs2, a21 = f1 * rs2, a22 = f2 * rs2;

    float w0_ = z0 - 10000.f * a20, w1_ = z1 - 10000.f * a21, w2_ = z2 - 10000.f * a22;
    float mx3 = fmaxf(fmaxf(w0_, w1_), w2_);
    float h0 = expf(w0_ - mx3), h1 = expf(w1_ - mx3), h2 = expf(w2_ - mx3);
    float rs3 = 1.0f / (h0 + h1 + h2);
    float a30 = h0 * rs3, a31 = h1 * rs3, a32 = h2 * rs3;

    // ---- demand breakup (per-lane) ----
    float delta0 = a10 * C0 + a11 * C1 + a12 * C2;
    float d0 = delta0 - fmaxf(delta0 - dt, 0.f);
    float delta1 = a20 * C0 + a21 * C1 + a22 * C2;
    float d1 = delta1 - fmaxf(delta1 - (dt - d0), 0.f);
    float delta2 = a30 * C0 + a31 * C1 + a32 * C2;
    float d2 = delta2 - fmaxf(delta2 - (dt - d0 - d1), 0.f);

    float dg = a12 * d0 + a22 * d1 + a32 * d2;
    float dp = a11 * d0 + a21 * d1 + a31 * d2;
    float dd = (a10 * d0 + a20 * d1 + a30 * d2) * ETA_INV;

    float rs = (t == 0) ? 0.f : dd / S_ex;   // scaled r[t]; row 0 of i_t is zero

    // ---- scan 3: suffix scan of affine maps qs_i = A_i + B_i * qs_{i+1} ----
    float A  = __shfl_down(rs, 1, 32);       // rs[t+1]
    float mn = __shfl_down(m, 1, 32);        // m_in[t+1]
    float Bc = __expf(m - mn);               // <= 1 (m nondecreasing)
    if (t >= 23) { A = 0.f; Bc = 1.f; }      // identity maps at/after the tail
#pragma unroll
    for (int off = 1; off < 32; off <<= 1) {
        float Ao = __shfl_down(A, off, 32);
        float Bo = __shfl_down(Bc, off, 32);
        if (t + off < 23) { A = A + Bc * Ao; Bc = Bc * Bo; }
    }
    float qs = A;                            // = sum_{u>t} r_u * e^{m[t]-m[u-1]}

    float dc = __expf(gt - m) * qs * ETA_INV;  // exponent <= 0
    float ds = S * qs;

    // ---- stores: out[inst*120 + row*24 + t] ----
    if (act) {
        float* ob = out + (size_t)inst * 120 + t;
        ob[0]  = dg + dc;
        ob[24] = dp;
        ob[48] = ds;
        ob[72] = dc;
        ob[96] = dd;
    }
}

extern "C" void kernel_launch(void* const* d_in, const int* in_sizes, int n_in,
                              void* d_out, int out_size, void* d_ws, size_t ws_size,
                              hipStream_t stream) {
    const float* pi_g = (const float*)d_in[0];
    const float* pi_p = (const float*)d_in[1];
    const float* pi_s = (const float*)d_in[2];
    const float* pi_c = (const float*)d_in[3];
    const float* pi_d = (const float*)d_in[4];
    const float* d_t  = (const float*)d_in[5];
    const float* C_t  = (const float*)d_in[6];
    float* out = (float*)d_out;

    int n = in_sizes[0] / 24;                 // batch = 16384 instances
    int blocks = (n + 7) / 8;                 // 8 instances per 256-thread block
    gru_kernel<<<blocks, 256, 0, stream>>>(pi_g, pi_p, pi_s, pi_c, pi_d, d_t, C_t, out, n);
}

// Round 4
// 11.340 us; speedup vs baseline: 2.0729x; 1.0953x over previous
//
#include <hip/hip_runtime.h>
#include <cmath>

#define ETA_INV 1.0526315789473684f   // 1/0.95

// One 32-lane group per instance; lane t in [0,24) handles time slot t.
// All per-t scans done with width-32 wave shuffles; no LDS, no barriers.
__global__ __launch_bounds__(256) void gru_kernel(
    const float* __restrict__ pi_g, const float* __restrict__ pi_p,
    const float* __restrict__ pi_s, const float* __restrict__ pi_c,
    const float* __restrict__ pi_d, const float* __restrict__ d_t,
    const float* __restrict__ C,    float* __restrict__ out, int nInst)
{
    const int inst = blockIdx.x * 8 + (threadIdx.x >> 5);
    const int t    = threadIdx.x & 31;
    if (inst >= nInst) return;
    const bool act = (t < 24);

    // ---- loads (lanes 24-31 clamp to t=23; their values never escape) ----
    const int tc = act ? t : 23;
    const size_t b24 = (size_t)inst * 24 + tc;
    float p_g = pi_g[b24];
    float p_p = fmaxf(pi_p[b24], 0.f);
    float p_s = fmaxf(pi_s[b24], 0.f);
    float p_c = fmaxf(pi_c[b24], 0.f);
    float p_d = fmaxf(pi_d[b24], 0.f);
    float dt  = d_t[b24];
    const size_t b72 = (size_t)inst * 72 + 3 * tc;
    float C0 = C[b72], C1 = C[b72 + 1], C2 = C[b72 + 2];

    // ---- scan 1: cs[t] = sum_{k<t} pi_s_eta[k]  (shift + inclusive sum) ----
    float ps_eta = p_s * ETA_INV;
    float cs = __shfl_up(ps_eta, 1, 32);
    if (t == 0) cs = 0.f;
#pragma unroll
    for (int off = 1; off < 32; off <<= 1) {
        float o = __shfl_up(cs, off, 32);
        if (t >= off) cs += o;
    }

    // ---- g[t]; scan 2: online-softmax pair (m,S) inclusive scan ----
    float gt = -5.f * (p_c * (ETA_INV * ETA_INV) + p_g - cs);
    float m = gt, S = 1.f;
#pragma unroll
    for (int off = 1; off < 32; off <<= 1) {
        float mo = __shfl_up(m, off, 32);
        float So = __shfl_up(S, off, 32);
        if (t >= off) {
            float nm = fmaxf(m, mo);
            S = S * __expf(m - nm) + So * __expf(mo - nm);  // exponents <= 0
            m = nm;
        }
    }
    float m_ex = __shfl_up(m, 1, 32);   // exclusive prefix max of g
    float S_ex = __shfl_up(S, 1, 32);   // exclusive scaled sum (at scale m_ex)
    if (t == 0) { m_ex = -1e30f; S_ex = 0.f; }

    // ---- cascade (per-lane, independent): __expf is <=1ulp + |arg|*2^-24;
    //      amplified logit error vanishes where components contend ----
    float pi_t = cs - 0.2f * m_ex;                 // t=0 -> ~2e29 acts as +inf
    float X0 = pi_t + p_d * ETA_INV;
    float y0 = -10.f * X0, y1 = -10.f * p_p, y2 = -10.f * p_g;

    float mx1 = fmaxf(fmaxf(y0, y1), y2);
    float e0 = __expf(y0 - mx1), e1 = __expf(y1 - mx1), e2 = __expf(y2 - mx1);
    float rs1 = 1.0f / (e0 + e1 + e2);
    float a10 = e0 * rs1, a11 = e1 * rs1, a12 = e2 * rs1;

    float z0 = y0 - 10000.f * a10, z1 = y1 - 10000.f * a11, z2 = y2 - 10000.f * a12;
    float mx2 = fmaxf(fmaxf(z0, z1), z2);
    float f0 = __expf(z0 - mx2), f1 = __expf(z1 - mx2), f2 = __expf(z2 - mx2);
    float rs2 = 1.0f / (f0 + f1 + f2);
    float a20 = f0 * rs2, a21 = f1 * rs2, a22 = f2 * rs2;

    float w0_ = z0 - 10000.f * a20, w1_ = z1 - 10000.f * a21, w2_ = z2 - 10000.f * a22;
    float mx3 = fmaxf(fmaxf(w0_, w1_), w2_);
    float h0 = __expf(w0_ - mx3), h1 = __expf(w1_ - mx3), h2 = __expf(w2_ - mx3);
    float rs3 = 1.0f / (h0 + h1 + h2);
    float a30 = h0 * rs3, a31 = h1 * rs3, a32 = h2 * rs3;

    // ---- demand breakup (per-lane) ----
    float delta0 = a10 * C0 + a11 * C1 + a12 * C2;
    float d0 = delta0 - fmaxf(delta0 - dt, 0.f);
    float delta1 = a20 * C0 + a21 * C1 + a22 * C2;
    float d1 = delta1 - fmaxf(delta1 - (dt - d0), 0.f);
    float delta2 = a30 * C0 + a31 * C1 + a32 * C2;
    float d2 = delta2 - fmaxf(delta2 - (dt - d0 - d1), 0.f);

    float dg = a12 * d0 + a22 * d1 + a32 * d2;
    float dp = a11 * d0 + a21 * d1 + a31 * d2;
    float dd = (a10 * d0 + a20 * d1 + a30 * d2) * ETA_INV;

    float rs = (t == 0) ? 0.f : dd / S_ex;   // scaled r[t]; row 0 of i_t is zero

    // ---- scan 3: suffix scan of affine maps qs_i = A_i + B_i * qs_{i+1} ----
    float A  = __shfl_down(rs, 1, 32);       // rs[t+1]
    float mn = __shfl_down(m, 1, 32);        // m_in[t+1]
    float Bc = __expf(m - mn);               // <= 1 (m nondecreasing)
    if (t >= 23) { A = 0.f; Bc = 1.f; }      // identity maps at/after the tail
#pragma unroll
    for (int off = 1; off < 32; off <<= 1) {
        float Ao = __shfl_down(A, off, 32);
        float Bo = __shfl_down(Bc, off, 32);
        if (t + off < 23) { A = A + Bc * Ao; Bc = Bc * Bo; }
    }
    float qs = A;                            // = sum_{u>t} r_u * e^{m[t]-m[u-1]}

    float dc = __expf(gt - m) * qs * ETA_INV;  // exponent <= 0
    float ds = S * qs;

    // ---- stores: out[inst*120 + row*24 + t] ----
    if (act) {
        float* ob = out + (size_t)inst * 120 + t;
        ob[0]  = dg + dc;
        ob[24] = dp;
        ob[48] = ds;
        ob[72] = dc;
        ob[96] = dd;
    }
}

extern "C" void kernel_launch(void* const* d_in, const int* in_sizes, int n_in,
                              void* d_out, int out_size, void* d_ws, size_t ws_size,
                              hipStream_t stream) {
    const float* pi_g = (const float*)d_in[0];
    const float* pi_p = (const float*)d_in[1];
    const float* pi_s = (const float*)d_in[2];
    const float* pi_c = (const float*)d_in[3];
    const float* pi_d = (const float*)d_in[4];
    const float* d_t  = (const float*)d_in[5];
    const float* C_t  = (const float*)d_in[6];
    float* out = (float*)d_out;

    int n = in_sizes[0] / 24;                 // batch = 16384 instances
    int blocks = (n + 7) / 8;                 // 8 instances per 256-thread block
    gru_kernel<<<blocks, 256, 0, stream>>>(pi_g, pi_p, pi_s, pi_c, pi_d, d_t, C_t, out, n);
}

// Round 5
// 11.048 us; speedup vs baseline: 2.1278x; 1.0265x over previous
//
#include <hip/hip_runtime.h>
#include <cmath>

#define ETA_INV 1.0526315789473684f   // 1/0.95

// One 32-lane group per instance; lane t in [0,24) handles time slot t.
// All per-t scans done with width-32 wave shuffles; no LDS, no barriers.
// __launch_bounds__(256,8): force <=64 VGPR -> 8 waves/SIMD for latency hiding.
__global__ __launch_bounds__(256, 8) void gru_kernel(
    const float* __restrict__ pi_g, const float* __restrict__ pi_p,
    const float* __restrict__ pi_s, const float* __restrict__ pi_c,
    const float* __restrict__ pi_d, const float* __restrict__ d_t,
    const float* __restrict__ C,    float* __restrict__ out, int nInst)
{
    const int inst = blockIdx.x * 8 + (threadIdx.x >> 5);
    const int t    = threadIdx.x & 31;
    if (inst >= nInst) return;
    const bool act = (t < 24);

    // ---- loads (lanes 24-31 clamp to t=23; their values never escape) ----
    const int tc = act ? t : 23;
    const size_t b24 = (size_t)inst * 24 + tc;
    float p_g = pi_g[b24];
    float p_p = fmaxf(pi_p[b24], 0.f);
    float p_s = fmaxf(pi_s[b24], 0.f);
    float p_c = fmaxf(pi_c[b24], 0.f);
    float p_d = fmaxf(pi_d[b24], 0.f);
    float dt  = d_t[b24];
    const size_t b72 = (size_t)inst * 72 + 3 * tc;
    float C0 = C[b72], C1 = C[b72 + 1], C2 = C[b72 + 2];

    // ---- scan 1: cs[t] = sum_{k<t} pi_s_eta[k]  (shift + inclusive sum) ----
    float ps_eta = p_s * ETA_INV;
    float cs = __shfl_up(ps_eta, 1, 32);
    if (t == 0) cs = 0.f;
#pragma unroll
    for (int off = 1; off < 32; off <<= 1) {
        float o = __shfl_up(cs, off, 32);
        if (t >= off) cs += o;
    }

    // ---- g[t]; scan 2: online-softmax pair (m,S) inclusive scan.
    //      nm = max(m,mo) => one exp is always 1: single-exp combine. ----
    float gt = -5.f * (p_c * (ETA_INV * ETA_INV) + p_g - cs);
    float m = gt, S = 1.f;
#pragma unroll
    for (int off = 1; off < 32; off <<= 1) {
        float mo = __shfl_up(m, off, 32);
        float So = __shfl_up(S, off, 32);
        if (t >= off) {
            float e = __expf(-fabsf(m - mo));      // exp of the loser's deficit
            bool mge = (m >= mo);
            S = mge ? (S + So * e) : (S * e + So);
            m = mge ? m : mo;
        }
    }
    float m_ex = __shfl_up(m, 1, 32);   // exclusive prefix max of g
    float S_ex = __shfl_up(S, 1, 32);   // exclusive scaled sum (at scale m_ex)
    if (t == 0) { m_ex = -1e30f; S_ex = 0.f; }

    // ---- cascade (per-lane, independent) ----
    float pi_t = cs - 0.2f * m_ex;                 // t=0 -> ~2e29 acts as +inf
    float X0 = pi_t + p_d * ETA_INV;
    float y0 = -10.f * X0, y1 = -10.f * p_p, y2 = -10.f * p_g;

    float mx1 = fmaxf(fmaxf(y0, y1), y2);
    float e0 = __expf(y0 - mx1), e1 = __expf(y1 - mx1), e2 = __expf(y2 - mx1);
    float rs1 = 1.0f / (e0 + e1 + e2);
    float a10 = e0 * rs1, a11 = e1 * rs1, a12 = e2 * rs1;

    float z0 = y0 - 10000.f * a10, z1 = y1 - 10000.f * a11, z2 = y2 - 10000.f * a12;
    float mx2 = fmaxf(fmaxf(z0, z1), z2);
    float f0 = __expf(z0 - mx2), f1 = __expf(z1 - mx2), f2 = __expf(z2 - mx2);
    float rs2 = 1.0f / (f0 + f1 + f2);
    float a20 = f0 * rs2, a21 = f1 * rs2, a22 = f2 * rs2;

    float w0_ = z0 - 10000.f * a20, w1_ = z1 - 10000.f * a21, w2_ = z2 - 10000.f * a22;
    float mx3 = fmaxf(fmaxf(w0_, w1_), w2_);
    float h0 = __expf(w0_ - mx3), h1 = __expf(w1_ - mx3), h2 = __expf(w2_ - mx3);
    float rs3 = 1.0f / (h0 + h1 + h2);
    float a30 = h0 * rs3, a31 = h1 * rs3, a32 = h2 * rs3;

    // ---- demand breakup (per-lane) ----
    float delta0 = a10 * C0 + a11 * C1 + a12 * C2;
    float d0 = delta0 - fmaxf(delta0 - dt, 0.f);
    float delta1 = a20 * C0 + a21 * C1 + a22 * C2;
    float d1 = delta1 - fmaxf(delta1 - (dt - d0), 0.f);
    float delta2 = a30 * C0 + a31 * C1 + a32 * C2;
    float d2 = delta2 - fmaxf(delta2 - (dt - d0 - d1), 0.f);

    float dg = a12 * d0 + a22 * d1 + a32 * d2;
    float dp = a11 * d0 + a21 * d1 + a31 * d2;
    float dd = (a10 * d0 + a20 * d1 + a30 * d2) * ETA_INV;

    float rs = (t == 0) ? 0.f : dd / S_ex;   // scaled r[t]; row 0 of i_t is zero

    // ---- scan 3: suffix scan of affine maps qs_i = A_i + B_i * qs_{i+1} ----
    float A  = __shfl_down(rs, 1, 32);       // rs[t+1]
    float mn = __shfl_down(m, 1, 32);        // m_in[t+1]
    float Bc = __expf(m - mn);               // <= 1 (m nondecreasing)
    if (t >= 23) { A = 0.f; Bc = 1.f; }      // identity maps at/after the tail
#pragma unroll
    for (int off = 1; off < 32; off <<= 1) {
        float Ao = __shfl_down(A, off, 32);
        float Bo = __shfl_down(Bc, off, 32);
        if (t + off < 23) { A = A + Bc * Ao; Bc = Bc * Bo; }
    }
    float qs = A;                            // = sum_{u>t} r_u * e^{m[t]-m[u-1]}

    float dc = __expf(gt - m) * qs * ETA_INV;  // exponent <= 0
    float ds = S * qs;

    // ---- stores: out[inst*120 + row*24 + t] ----
    if (act) {
        float* ob = out + (size_t)inst * 120 + t;
        ob[0]  = dg + dc;
        ob[24] = dp;
        ob[48] = ds;
        ob[72] = dc;
        ob[96] = dd;
    }
}

extern "C" void kernel_launch(void* const* d_in, const int* in_sizes, int n_in,
                              void* d_out, int out_size, void* d_ws, size_t ws_size,
                              hipStream_t stream) {
    const float* pi_g = (const float*)d_in[0];
    const float* pi_p = (const float*)d_in[1];
    const float* pi_s = (const float*)d_in[2];
    const float* pi_c = (const float*)d_in[3];
    const float* pi_d = (const float*)d_in[4];
    const float* d_t  = (const float*)d_in[5];
    const float* C_t  = (const float*)d_in[6];
    float* out = (float*)d_out;

    int n = in_sizes[0] / 24;                 // batch = 16384 instances
    int blocks = (n + 7) / 8;                 // 8 instances per 256-thread block
    gru_kernel<<<blocks, 256, 0, stream>>>(pi_g, pi_p, pi_s, pi_c, pi_d, d_t, C_t, out, n);
}